// Round 8
// baseline (618.170 us; speedup 1.0000x reference)
//
#include <hip/hip_runtime.h>
#include <hip/hip_bf16.h>
#include <stdint.h>

// Problem constants (fixed by the reference)
#define N_ 16384
#define M_ 4096
#define D_ 256
#define O_ 256

// Workspace layout (bytes), total ~2.3 MB
#define WS_T    0          // float[N]   exp(sf+ba)   64 KB
#define WS_U    65536      // float[M]   exp(sc)      16 KB
#define WS_R    81920      // float[D]   colsum(Hc)    1 KB
#define WS_WTP  98304      // ushort     Wt packed   128 KB
#define WS_BP   229376     // ushort     Hc packed     2 MB

typedef float  f32x4  __attribute__((ext_vector_type(4)));
typedef short  short8 __attribute__((ext_vector_type(8)));

// fp32 -> bf16 (RNE). Inputs are finite so no NaN handling.
__device__ __forceinline__ unsigned short f2bf(float f) {
  uint32_t u = __float_as_uint(f);
  u += 0x7FFFu + ((u >> 16) & 1u);
  return (unsigned short)(u >> 16);
}
// packed pair fp32 -> bf16
__device__ __forceinline__ uint32_t cvtpk(float a, float b) {
  __hip_bfloat162 h = __float22bfloat162_rn(float2{a, b});
  uint32_t u;
  __builtin_memcpy(&u, &h, 4);
  return u;
}

// ---------------------------------------------------------------------------
// Prep 1: per-row dot with weight vector, then exp(dot + bias).
__global__ __launch_bounds__(256) void rowdot_exp_kernel(
    const float* __restrict__ X, const float* __restrict__ w,
    const float* __restrict__ bias, float* __restrict__ outv) {
  int wv = threadIdx.x >> 6, lane = threadIdx.x & 63;
  int row = blockIdx.x * 4 + wv;
  const float4* x4 = (const float4*)(X + (size_t)row * D_);
  const float4* w4 = (const float4*)w;
  float4 xa = x4[lane], wa4 = w4[lane];
  float s = xa.x * wa4.x + xa.y * wa4.y + xa.z * wa4.z + xa.w * wa4.w;
#pragma unroll
  for (int off = 32; off > 0; off >>= 1) s += __shfl_xor(s, off);
  if (lane == 0) outv[row] = expf(s + (bias ? bias[0] : 0.0f));
}

// ---------------------------------------------------------------------------
// Prep 2: Hc [M,D] fp32 -> BP fragment-major bf16 (standard k-order) + colsum.
// BP[((kg*16 + cg)*64 + lane)*8 + j] = bf16(Hc[kg*32+q*8+j][cg*16+m]), lane=q*16+m.
__global__ __launch_bounds__(256) void hc_pack_kernel(
    const float* __restrict__ Hc, unsigned short* __restrict__ BP,
    float* __restrict__ R) {
  __shared__ float tile[64][65];
  __shared__ float red[4][64];
  int bk = blockIdx.x >> 2;   // 64 tiles along M (k)
  int bc = blockIdx.x & 3;    // 4 tiles along D (col)
  int k0 = bk * 64, col0 = bc * 64;
  int t = threadIdx.x;
  int lane = t & 63, wv = t >> 6;
  int m = lane & 15, q = lane >> 4;
  float colsum = 0.0f;
#pragma unroll
  for (int i = 0; i < 16; ++i) {
    int e = t + 256 * i;
    int kk = e >> 6, cc = e & 63;
    float v = Hc[(size_t)(k0 + kk) * D_ + col0 + cc];
    tile[kk][cc] = v;
    colsum += v;
  }
  red[wv][t & 63] = colsum;
  __syncthreads();
  if (t < 64)
    atomicAdd(&R[col0 + t], red[0][t] + red[1][t] + red[2][t] + red[3][t]);
#pragma unroll
  for (int t8 = 0; t8 < 2; ++t8) {
    int tile_id = t8 * 4 + wv;
    int sub = tile_id >> 2, g = tile_id & 3;
    int kgg = bk * 2 + sub;
    int cgg = bc * 4 + g;
    short8 v8;
#pragma unroll
    for (int j = 0; j < 8; ++j)
      v8[j] = (short)f2bf(tile[sub * 32 + q * 8 + j][g * 16 + m]);
    *(short8*)(BP + ((size_t)(kgg * 16 + cgg) * 64 + lane) * 8) = v8;
  }
}

// ---------------------------------------------------------------------------
// Prep 3: Wt [O,D] fp32 -> WtP fragment-major bf16 (kg 0..7, cg 0..15).
__global__ __launch_bounds__(256) void wt_pack_kernel(
    const float* __restrict__ Wt, unsigned short* __restrict__ WtP) {
  int t = blockIdx.x * 256 + threadIdx.x;    // 0..8191
  int lane = t & 63, cg = (t >> 6) & 15, kg = t >> 10;
  int m = lane & 15, q = lane >> 4;
  const float* src = Wt + (size_t)(cg * 16 + m) * D_ + kg * 32 + q * 8;
  float4 w0 = *(const float4*)src, w1 = *(const float4*)(src + 4);
  short8 v8;
  v8[0] = (short)f2bf(w0.x); v8[1] = (short)f2bf(w0.y);
  v8[2] = (short)f2bf(w0.z); v8[3] = (short)f2bf(w0.w);
  v8[4] = (short)f2bf(w1.x); v8[5] = (short)f2bf(w1.y);
  v8[6] = (short)f2bf(w1.z); v8[7] = (short)f2bf(w1.w);
  *(short8*)(WtP + (size_t)t * 8) = v8;
}

// ---------------------------------------------------------------------------
// transform 8 adj values -> bf16 A'-fragment (slot j: k = base + q*8 + j) + row-sum
__device__ __forceinline__ short8 transform8(float4 A0, float4 A1, float t,
                                             float4 u0, float4 u1, float& rs) {
  float p0 = fmaf(A0.x, t * u0.x, -A0.x);
  float p1 = fmaf(A0.y, t * u0.y, -A0.y);
  float p2 = fmaf(A0.z, t * u0.z, -A0.z);
  float p3 = fmaf(A0.w, t * u0.w, -A0.w);
  float p4 = fmaf(A1.x, t * u1.x, -A1.x);
  float p5 = fmaf(A1.y, t * u1.y, -A1.y);
  float p6 = fmaf(A1.z, t * u1.z, -A1.z);
  float p7 = fmaf(A1.w, t * u1.w, -A1.w);
  rs += ((p0 + p1) + (p2 + p3)) + ((p4 + p5) + (p6 + p7));
  union { short8 s; uint32_t u[4]; } r;
  r.u[0] = cvtpk(p0, p1);
  r.u[1] = cvtpk(p2, p3);
  r.u[2] = cvtpk(p4, p5);
  r.u[3] = cvtpk(p6, p7);
  return r.s;
}

// ---------------------------------------------------------------------------
// Mega-kernel: one pass over adj does EVERYTHING after the preps.
//   Block = 32 rows x all 256 cols x full K=4096. 512 thr = 8 waves; waves
//   split K (512 each) so adj is read exactly once globally (no duplication).
//   Per wave: acc[2][16] (32x256 tile, 128 regs -> AGPR-backed). A' built in
//   registers (transform8), B fragments streamed from prepacked BP (L2-hot),
//   barrier-free K loop with depth-1 adj register prefetch.
//   Combine: partial C via LDS fp32 atomics; denoms via LDS reduce; then
//   attn = (C+R)/(L+M)+Hf -> LDS bf16 -> O-GEMM vs WtP -> relu -> out.
// Grid = N/32 = 512 blocks -> 1 block/CU (2 waves/SIMD at ~210 VGPR).
__global__ __launch_bounds__(512, 2) void mega_kernel(
    const float* __restrict__ adj, const unsigned short* __restrict__ BP,
    const float* __restrict__ tv, const float* __restrict__ uv,
    const float* __restrict__ Rv, const float* __restrict__ Hf,
    const unsigned short* __restrict__ WtP, const float* __restrict__ bt,
    float* __restrict__ out) {
  __shared__ float u_lds[M_];                    // 16 KB
  __shared__ float part[32][260];                // 33.3 KB fp32 C accumulator
  __shared__ float redd[8][32];                  // per-wave denom partials
  __shared__ float Lrow[32];
  __shared__ alignas(16) unsigned short attn[32][264];  // 16.9 KB

  int tid = threadIdx.x;
  int w = tid >> 6, lane = tid & 63;
  int q = lane >> 4, m = lane & 15;
  int i0 = blockIdx.x * 32;

  for (int i = tid; i < M_; i += 512) u_lds[i] = uv[i];
  {
    float* pz = &part[0][0];
    for (int i = tid; i < 32 * 260; i += 512) pz[i] = 0.0f;
  }

  float t0 = tv[i0 + m], t1 = tv[i0 + 16 + m];
  // wave w owns K range [w*512, w*512+512) = ksteps kg = w*16 .. w*16+15
  const float* a0 = adj + (size_t)(i0 + m) * M_ + w * 512 + q * 8;
  const float* a1 = a0 + (size_t)16 * M_;

  f32x4 acc[2][16];
#pragma unroll
  for (int s = 0; s < 2; ++s)
#pragma unroll
    for (int n = 0; n < 16; ++n) acc[s][n] = (f32x4){0.f, 0.f, 0.f, 0.f};
  float rs0 = 0.0f, rs1 = 0.0f;

  __syncthreads();  // u_lds + part zero ready

  // depth-1 adj register prefetch
  float4 pa0 = *(const float4*)(a0);
  float4 pa1 = *(const float4*)(a0 + 4);
  float4 pb0 = *(const float4*)(a1);
  float4 pb1 = *(const float4*)(a1 + 4);

  for (int i = 0; i < 16; ++i) {
    int inx = (i + 1 < 16) ? i + 1 : 0;        // wrap: harmless reload
    float4 na0 = *(const float4*)(a0 + inx * 32);
    float4 na1 = *(const float4*)(a0 + inx * 32 + 4);
    float4 nb0 = *(const float4*)(a1 + inx * 32);
    float4 nb1 = *(const float4*)(a1 + inx * 32 + 4);

    int kg = w * 16 + i;
    float4 u0 = *(const float4*)&u_lds[kg * 32 + q * 8];
    float4 u1 = *(const float4*)&u_lds[kg * 32 + q * 8 + 4];
    short8 af0 = transform8(pa0, pa1, t0, u0, u1, rs0);
    short8 af1 = transform8(pb0, pb1, t1, u0, u1, rs1);

    // 16 col-groups, B register rotation (depth-1)
    const unsigned short* bk = BP + (size_t)(kg * 16) * 512 + (size_t)lane * 8;
    short8 bcur = *(const short8*)(bk);
#pragma unroll
    for (int n = 0; n < 16; ++n) {
      short8 bnext = bcur;
      if (n < 15) bnext = *(const short8*)(bk + (size_t)(n + 1) * 512);
      acc[0][n] = __builtin_amdgcn_mfma_f32_16x16x32_bf16(af0, bcur, acc[0][n], 0, 0, 0);
      acc[1][n] = __builtin_amdgcn_mfma_f32_16x16x32_bf16(af1, bcur, acc[1][n], 0, 0, 0);
      bcur = bnext;
    }
    pa0 = na0; pa1 = na1; pb0 = nb0; pb1 = nb1;
  }

  // per-wave denominator partials: reduce over the 4 k-quads
  rs0 += __shfl_xor(rs0, 16); rs0 += __shfl_xor(rs0, 32);
  rs1 += __shfl_xor(rs1, 16); rs1 += __shfl_xor(rs1, 32);
  if (lane < 16) { redd[w][m] = rs0; redd[w][16 + m] = rs1; }

  // partial C -> LDS fp32 atomic accumulate (8 adds/address total)
#pragma unroll
  for (int s = 0; s < 2; ++s)
#pragma unroll
    for (int n = 0; n < 16; ++n) {
      int col = n * 16 + m;
#pragma unroll
      for (int r = 0; r < 4; ++r)
        atomicAdd(&part[s * 16 + q * 4 + r][col], acc[s][n][r]);  // C/D: row=(lane>>4)*4+reg
    }
  __syncthreads();

  if (tid < 32) {
    float S = 0.0f;
#pragma unroll
    for (int ww = 0; ww < 8; ++ww) S += redd[ww][tid];
    Lrow[tid] = S;
  }
  __syncthreads();

  // attn = (C + R)/(L + M) + Hf -> bf16 LDS. Wave w: rows w*4..w*4+3;
  // lane handles col pairs (2*lane, 2*lane+1) in each 128-col half.
#pragma unroll
  for (int rr = 0; rr < 4; ++rr) {
    int r = w * 4 + rr;
    float invL = 1.0f / (Lrow[r] + (float)M_);
    size_t grow = (size_t)(i0 + r) * D_;
#pragma unroll
    for (int h = 0; h < 2; ++h) {
      int c = h * 128 + 2 * lane;
      float2 pv = *(const float2*)&part[r][c];
      float2 rv = *(const float2*)(Rv + c);
      float2 hv = *(const float2*)(Hf + grow + c);
      float v0 = fmaf(pv.x + rv.x, invL, hv.x);
      float v1 = fmaf(pv.y + rv.y, invL, hv.y);
      *(uint32_t*)&attn[r][c] = cvtpk(v0, v1);
    }
  }
  __syncthreads();

  // O-GEMM: out = relu(attn @ Wt^T + bt). 8 waves = 2 rtiles x 4 col-64s.
  int rtile = w & 1, c64 = w >> 1;
  f32x4 facc[4];
#pragma unroll
  for (int n = 0; n < 4; ++n) facc[n] = (f32x4){0.f, 0.f, 0.f, 0.f};
#pragma unroll
  for (int kf = 0; kf < 8; ++kf) {
    short8 af = *(const short8*)&attn[rtile * 16 + m][kf * 32 + q * 8];
#pragma unroll
    for (int n = 0; n < 4; ++n) {
      int cg = c64 * 4 + n;
      short8 bf = *(const short8*)(WtP + ((size_t)(kf * 16 + cg) * 64 + lane) * 8);
      facc[n] = __builtin_amdgcn_mfma_f32_16x16x32_bf16(af, bf, facc[n], 0, 0, 0);
    }
  }
#pragma unroll
  for (int n = 0; n < 4; ++n) {
    int col = c64 * 64 + n * 16 + m;
    float b = bt[col];
#pragma unroll
    for (int r = 0; r < 4; ++r) {
      size_t row = (size_t)i0 + rtile * 16 + q * 4 + r;
      out[row * O_ + col] = fmaxf(facc[n][r] + b, 0.0f);
    }
  }
}

// ---------------------------------------------------------------------------
extern "C" void kernel_launch(void* const* d_in, const int* in_sizes, int n_in,
                              void* d_out, int out_size, void* d_ws, size_t ws_size,
                              hipStream_t stream) {
  const float* Hf  = (const float*)d_in[0];  // [N,D]
  const float* Hc  = (const float*)d_in[1];  // [M,D]
  const float* adj = (const float*)d_in[2];  // [N,M]
  const float* wa  = (const float*)d_in[3];  // [2D]
  const float* ba  = (const float*)d_in[4];  // [1]
  const float* Wt  = (const float*)d_in[5];  // [O,D]
  const float* bt  = (const float*)d_in[6];  // [O]
  float* out = (float*)d_out;

  char* ws = (char*)d_ws;
  float* tv = (float*)(ws + WS_T);
  float* uv = (float*)(ws + WS_U);
  float* Rv = (float*)(ws + WS_R);
  unsigned short* WtP = (unsigned short*)(ws + WS_WTP);
  unsigned short* BP  = (unsigned short*)(ws + WS_BP);

  hipMemsetAsync(Rv, 0, D_ * sizeof(float), stream);  // atomic target

  rowdot_exp_kernel<<<N_ / 4, 256, 0, stream>>>(Hf, wa, ba, tv);           // t = exp(sf+ba)
  rowdot_exp_kernel<<<M_ / 4, 256, 0, stream>>>(Hc, wa + D_, nullptr, uv); // u = exp(sc)
  hc_pack_kernel<<<256, 256, 0, stream>>>(Hc, BP, Rv);
  wt_pack_kernel<<<32, 256, 0, stream>>>(Wt, WtP);

  mega_kernel<<<N_ / 32, 512, 0, stream>>>(adj, BP, tv, uv, Rv, Hf, WtP, bt, out);
}

// Round 9
// 522.081 us; speedup vs baseline: 1.1840x; 1.1840x over previous
//
#include <hip/hip_runtime.h>
#include <hip/hip_bf16.h>
#include <stdint.h>

// Problem constants (fixed by the reference)
#define N_ 16384
#define M_ 4096
#define D_ 256
#define O_ 256

// Workspace layout (bytes), total ~2.3 MB
#define WS_T    0          // float[N]   exp(sf+ba)   64 KB
#define WS_U    65536      // float[M]   exp(sc)      16 KB
#define WS_R    81920      // float[D]   colsum(Hc)    1 KB
#define WS_WTP  98304      // ushort     Wt packed   128 KB
#define WS_BP   229376     // ushort     Hc packed     2 MB

typedef float  f32x4  __attribute__((ext_vector_type(4)));
typedef short  short8 __attribute__((ext_vector_type(8)));

// fp32 -> bf16 (RNE). Inputs are finite so no NaN handling.
__device__ __forceinline__ unsigned short f2bf(float f) {
  uint32_t u = __float_as_uint(f);
  u += 0x7FFFu + ((u >> 16) & 1u);
  return (unsigned short)(u >> 16);
}
// packed pair fp32 -> bf16
__device__ __forceinline__ uint32_t cvtpk(float a, float b) {
  __hip_bfloat162 h = __float22bfloat162_rn(float2{a, b});
  uint32_t u;
  __builtin_memcpy(&u, &h, 4);
  return u;
}

// ---------------------------------------------------------------------------
// Prep 1: per-row dot with weight vector, then exp(dot + bias).
__global__ __launch_bounds__(256) void rowdot_exp_kernel(
    const float* __restrict__ X, const float* __restrict__ w,
    const float* __restrict__ bias, float* __restrict__ outv) {
  int wv = threadIdx.x >> 6, lane = threadIdx.x & 63;
  int row = blockIdx.x * 4 + wv;
  const float4* x4 = (const float4*)(X + (size_t)row * D_);
  const float4* w4 = (const float4*)w;
  float4 xa = x4[lane], wa4 = w4[lane];
  float s = xa.x * wa4.x + xa.y * wa4.y + xa.z * wa4.z + xa.w * wa4.w;
#pragma unroll
  for (int off = 32; off > 0; off >>= 1) s += __shfl_xor(s, off);
  if (lane == 0) outv[row] = expf(s + (bias ? bias[0] : 0.0f));
}

// ---------------------------------------------------------------------------
// Prep 2: Hc [M,D] fp32 -> BP fragment-major bf16 (standard k-order) + colsum.
// BP[((kg*16 + cg)*64 + lane)*8 + j] = bf16(Hc[kg*32+q*8+j][cg*16+m]), lane=q*16+m.
__global__ __launch_bounds__(256) void hc_pack_kernel(
    const float* __restrict__ Hc, unsigned short* __restrict__ BP,
    float* __restrict__ R) {
  __shared__ float tile[64][65];
  __shared__ float red[4][64];
  int bk = blockIdx.x >> 2;   // 64 tiles along M (k)
  int bc = blockIdx.x & 3;    // 4 tiles along D (col)
  int k0 = bk * 64, col0 = bc * 64;
  int t = threadIdx.x;
  int lane = t & 63, wv = t >> 6;
  int m = lane & 15, q = lane >> 4;
  float colsum = 0.0f;
#pragma unroll
  for (int i = 0; i < 16; ++i) {
    int e = t + 256 * i;
    int kk = e >> 6, cc = e & 63;
    float v = Hc[(size_t)(k0 + kk) * D_ + col0 + cc];
    tile[kk][cc] = v;
    colsum += v;
  }
  red[wv][t & 63] = colsum;
  __syncthreads();
  if (t < 64)
    atomicAdd(&R[col0 + t], red[0][t] + red[1][t] + red[2][t] + red[3][t]);
#pragma unroll
  for (int t8 = 0; t8 < 2; ++t8) {
    int tile_id = t8 * 4 + wv;
    int sub = tile_id >> 2, g = tile_id & 3;
    int kgg = bk * 2 + sub;
    int cgg = bc * 4 + g;
    short8 v8;
#pragma unroll
    for (int j = 0; j < 8; ++j)
      v8[j] = (short)f2bf(tile[sub * 32 + q * 8 + j][g * 16 + m]);
    *(short8*)(BP + ((size_t)(kgg * 16 + cgg) * 64 + lane) * 8) = v8;
  }
}

// ---------------------------------------------------------------------------
// Prep 3: Wt [O,D] fp32 -> WtP fragment-major bf16 (kg 0..7, cg 0..15).
__global__ __launch_bounds__(256) void wt_pack_kernel(
    const float* __restrict__ Wt, unsigned short* __restrict__ WtP) {
  int t = blockIdx.x * 256 + threadIdx.x;    // 0..8191
  int lane = t & 63, cg = (t >> 6) & 15, kg = t >> 10;
  int m = lane & 15, q = lane >> 4;
  const float* src = Wt + (size_t)(cg * 16 + m) * D_ + kg * 32 + q * 8;
  float4 w0 = *(const float4*)src, w1 = *(const float4*)(src + 4);
  short8 v8;
  v8[0] = (short)f2bf(w0.x); v8[1] = (short)f2bf(w0.y);
  v8[2] = (short)f2bf(w0.z); v8[3] = (short)f2bf(w0.w);
  v8[4] = (short)f2bf(w1.x); v8[5] = (short)f2bf(w1.y);
  v8[6] = (short)f2bf(w1.z); v8[7] = (short)f2bf(w1.w);
  *(short8*)(WtP + (size_t)t * 8) = v8;
}

// ---------------------------------------------------------------------------
// transform 8 adj values -> bf16 A'-fragment (slot j: k = base + q*8 + j) + row-sum
__device__ __forceinline__ short8 transform8(float4 A0, float4 A1, float t,
                                             float4 u0, float4 u1, float& rs) {
  float p0 = fmaf(A0.x, t * u0.x, -A0.x);
  float p1 = fmaf(A0.y, t * u0.y, -A0.y);
  float p2 = fmaf(A0.z, t * u0.z, -A0.z);
  float p3 = fmaf(A0.w, t * u0.w, -A0.w);
  float p4 = fmaf(A1.x, t * u1.x, -A1.x);
  float p5 = fmaf(A1.y, t * u1.y, -A1.y);
  float p6 = fmaf(A1.z, t * u1.z, -A1.z);
  float p7 = fmaf(A1.w, t * u1.w, -A1.w);
  rs += ((p0 + p1) + (p2 + p3)) + ((p4 + p5) + (p6 + p7));
  union { short8 s; uint32_t u[4]; } r;
  r.u[0] = cvtpk(p0, p1);
  r.u[1] = cvtpk(p2, p3);
  r.u[2] = cvtpk(p4, p5);
  r.u[3] = cvtpk(p6, p7);
  return r.s;
}

// ---------------------------------------------------------------------------
// Fused one-pass kernel (low-register edition):
//   Block = 32 rows x 256 cols x full K=4096, 512 thr = 8 waves arranged as
//   4 col-quarters x 2 K-halves. Per wave: 32 rows x 64 cols x K-half 2048
//   -> acc[2][4] = 32 regs (R7-proven budget). adj read once per block from
//   HBM; the 4 colq waves re-read the same lines via L1/L2 (intra-CU dup is
//   cheap). A' built in registers, B fragments from prepacked BP (L2-hot),
//   barrier-free K loop with depth-1 X/Y register prefetch on adj + B.
//   Combine: K-half partials via LDS fp32 atomics (2 adds/address); denoms
//   from colq==0 waves; then attn=(C+R)/(L+M)+Hf -> LDS bf16 -> O-GEMM -> out.
// Grid = N/32 = 512 blocks, LDS ~65 KB, VGPR<=128 -> 2 blocks/CU = 16 waves/CU,
// exactly one dispatch round.
__global__ __launch_bounds__(512, 4) void fused_kernel(
    const float* __restrict__ adj, const unsigned short* __restrict__ BP,
    const float* __restrict__ tv, const float* __restrict__ uv,
    const float* __restrict__ Rv, const float* __restrict__ Hf,
    const unsigned short* __restrict__ WtP, const float* __restrict__ bt,
    float* __restrict__ out) {
  __shared__ float u_lds[M_];                    // 16 KB
  __shared__ float part[32][260];                // 33.3 KB fp32 C accumulator
  __shared__ float redd[2][32];                  // per-khalf denom partials
  __shared__ float Lrow[32];
  __shared__ alignas(16) unsigned short attn[32][264];  // 16.9 KB

  int tid = threadIdx.x;
  int w = tid >> 6, lane = tid & 63;
  int q = lane >> 4, m = lane & 15;
  int colq = w & 3, khalf = w >> 2;
  int i0 = blockIdx.x * 32;

  for (int i = tid; i < M_; i += 512) u_lds[i] = uv[i];
  {
    float* pz = &part[0][0];
    for (int i = tid; i < 32 * 260; i += 512) pz[i] = 0.0f;
  }

  float t0 = tv[i0 + m], t1 = tv[i0 + 16 + m];
  const float* a0 = adj + (size_t)(i0 + m) * M_ + khalf * 2048 + q * 8;
  const float* a1 = a0 + (size_t)16 * M_;
  // B fragment base for (kstep kk, colgroup n): bb + (kk*16 + n)*512
  const unsigned short* bb =
      BP + ((size_t)(khalf * 64) * 16 + colq * 4) * 512 + (size_t)lane * 8;
  const float* ub = u_lds + khalf * 2048 + q * 8;

  f32x4 acc[2][4];
#pragma unroll
  for (int s = 0; s < 2; ++s)
#pragma unroll
    for (int n = 0; n < 4; ++n) acc[s][n] = (f32x4){0.f, 0.f, 0.f, 0.f};
  float rs0 = 0.0f, rs1 = 0.0f;

  __syncthreads();  // u_lds + part zero ready

  // depth-1 X/Y register prefetch: X = even ksteps, Y = odd ksteps
  float4 xa0 = *(const float4*)(a0);
  float4 xa1 = *(const float4*)(a0 + 4);
  float4 xb0 = *(const float4*)(a1);
  float4 xb1 = *(const float4*)(a1 + 4);
  float4 ya0 = *(const float4*)(a0 + 32);
  float4 ya1 = *(const float4*)(a0 + 36);
  float4 yb0 = *(const float4*)(a1 + 32);
  float4 yb1 = *(const float4*)(a1 + 36);
  short8 BX[4], BY[4];
#pragma unroll
  for (int n = 0; n < 4; ++n) BX[n] = *(const short8*)(bb + n * 512);
#pragma unroll
  for (int n = 0; n < 4; ++n) BY[n] = *(const short8*)(bb + 8192 + n * 512);

  for (int kk = 0; kk < 64; kk += 2) {
    // ---- kstep kk (set X); prefetch kk+2 into X
    {
      int k2 = (kk + 2) & 63;                  // wrap: harmless reload
      float4 na0 = *(const float4*)(a0 + k2 * 32);
      float4 na1 = *(const float4*)(a0 + k2 * 32 + 4);
      float4 nb0 = *(const float4*)(a1 + k2 * 32);
      float4 nb1 = *(const float4*)(a1 + k2 * 32 + 4);
      short8 nB[4];
#pragma unroll
      for (int n = 0; n < 4; ++n)
        nB[n] = *(const short8*)(bb + (size_t)k2 * 8192 + n * 512);

      float4 u0 = *(const float4*)(ub + kk * 32);
      float4 u1 = *(const float4*)(ub + kk * 32 + 4);
      short8 af0 = transform8(xa0, xa1, t0, u0, u1, rs0);
      short8 af1 = transform8(xb0, xb1, t1, u0, u1, rs1);
#pragma unroll
      for (int n = 0; n < 4; ++n) {
        acc[0][n] = __builtin_amdgcn_mfma_f32_16x16x32_bf16(af0, BX[n], acc[0][n], 0, 0, 0);
        acc[1][n] = __builtin_amdgcn_mfma_f32_16x16x32_bf16(af1, BX[n], acc[1][n], 0, 0, 0);
      }
      xa0 = na0; xa1 = na1; xb0 = nb0; xb1 = nb1;
#pragma unroll
      for (int n = 0; n < 4; ++n) BX[n] = nB[n];
    }
    // ---- kstep kk+1 (set Y); prefetch kk+3 into Y
    {
      int k3 = (kk + 3) & 63;
      float4 na0 = *(const float4*)(a0 + k3 * 32);
      float4 na1 = *(const float4*)(a0 + k3 * 32 + 4);
      float4 nb0 = *(const float4*)(a1 + k3 * 32);
      float4 nb1 = *(const float4*)(a1 + k3 * 32 + 4);
      short8 nB[4];
#pragma unroll
      for (int n = 0; n < 4; ++n)
        nB[n] = *(const short8*)(bb + (size_t)k3 * 8192 + n * 512);

      float4 u0 = *(const float4*)(ub + (kk + 1) * 32);
      float4 u1 = *(const float4*)(ub + (kk + 1) * 32 + 4);
      short8 af0 = transform8(ya0, ya1, t0, u0, u1, rs0);
      short8 af1 = transform8(yb0, yb1, t1, u0, u1, rs1);
#pragma unroll
      for (int n = 0; n < 4; ++n) {
        acc[0][n] = __builtin_amdgcn_mfma_f32_16x16x32_bf16(af0, BY[n], acc[0][n], 0, 0, 0);
        acc[1][n] = __builtin_amdgcn_mfma_f32_16x16x32_bf16(af1, BY[n], acc[1][n], 0, 0, 0);
      }
      ya0 = na0; ya1 = na1; yb0 = nb0; yb1 = nb1;
#pragma unroll
      for (int n = 0; n < 4; ++n) BY[n] = nB[n];
    }
  }

  // denominator partials (per khalf; colq==0 waves carry the result)
  rs0 += __shfl_xor(rs0, 16); rs0 += __shfl_xor(rs0, 32);
  rs1 += __shfl_xor(rs1, 16); rs1 += __shfl_xor(rs1, 32);
  if (colq == 0 && lane < 16) {
    redd[khalf][m] = rs0;
    redd[khalf][16 + m] = rs1;
  }

  // K-half partial C -> LDS fp32 atomic accumulate (2 adds/address)
#pragma unroll
  for (int s = 0; s < 2; ++s)
#pragma unroll
    for (int n = 0; n < 4; ++n) {
      int col = colq * 64 + n * 16 + m;
#pragma unroll
      for (int r = 0; r < 4; ++r)
        atomicAdd(&part[s * 16 + q * 4 + r][col], acc[s][n][r]);  // C/D: row=(lane>>4)*4+reg
    }
  __syncthreads();

  if (tid < 32) Lrow[tid] = redd[0][tid] + redd[1][tid];
  __syncthreads();

  // attn = (C + R)/(L + M) + Hf -> bf16 LDS. Wave w: rows w*4..w*4+3;
  // lane handles col pairs (2*lane, 2*lane+1) in each 128-col half.
#pragma unroll
  for (int rr = 0; rr < 4; ++rr) {
    int r = w * 4 + rr;
    float invL = 1.0f / (Lrow[r] + (float)M_);
    size_t grow = (size_t)(i0 + r) * D_;
#pragma unroll
    for (int h = 0; h < 2; ++h) {
      int c = h * 128 + 2 * lane;
      float2 pv = *(const float2*)&part[r][c];
      float2 rv = *(const float2*)(Rv + c);
      float2 hv = *(const float2*)(Hf + grow + c);
      float v0 = fmaf(pv.x + rv.x, invL, hv.x);
      float v1 = fmaf(pv.y + rv.y, invL, hv.y);
      *(uint32_t*)&attn[r][c] = cvtpk(v0, v1);
    }
  }
  __syncthreads();

  // O-GEMM: out = relu(attn @ Wt^T + bt). 8 waves = 2 rtiles x 4 col-64s.
  int rtile = w & 1, c64 = w >> 1;
  f32x4 facc[4];
#pragma unroll
  for (int n = 0; n < 4; ++n) facc[n] = (f32x4){0.f, 0.f, 0.f, 0.f};
#pragma unroll
  for (int kf = 0; kf < 8; ++kf) {
    short8 af = *(const short8*)&attn[rtile * 16 + m][kf * 32 + q * 8];
#pragma unroll
    for (int n = 0; n < 4; ++n) {
      int cg = c64 * 4 + n;
      short8 bf = *(const short8*)(WtP + ((size_t)(kf * 16 + cg) * 64 + lane) * 8);
      facc[n] = __builtin_amdgcn_mfma_f32_16x16x32_bf16(af, bf, facc[n], 0, 0, 0);
    }
  }
#pragma unroll
  for (int n = 0; n < 4; ++n) {
    int col = c64 * 64 + n * 16 + m;
    float b = bt[col];
#pragma unroll
    for (int r = 0; r < 4; ++r) {
      size_t row = (size_t)i0 + rtile * 16 + q * 4 + r;
      out[row * O_ + col] = fmaxf(facc[n][r] + b, 0.0f);
    }
  }
}

// ---------------------------------------------------------------------------
extern "C" void kernel_launch(void* const* d_in, const int* in_sizes, int n_in,
                              void* d_out, int out_size, void* d_ws, size_t ws_size,
                              hipStream_t stream) {
  const float* Hf  = (const float*)d_in[0];  // [N,D]
  const float* Hc  = (const float*)d_in[1];  // [M,D]
  const float* adj = (const float*)d_in[2];  // [N,M]
  const float* wa  = (const float*)d_in[3];  // [2D]
  const float* ba  = (const float*)d_in[4];  // [1]
  const float* Wt  = (const float*)d_in[5];  // [O,D]
  const float* bt  = (const float*)d_in[6];  // [O]
  float* out = (float*)d_out;

  char* ws = (char*)d_ws;
  float* tv = (float*)(ws + WS_T);
  float* uv = (float*)(ws + WS_U);
  float* Rv = (float*)(ws + WS_R);
  unsigned short* WtP = (unsigned short*)(ws + WS_WTP);
  unsigned short* BP  = (unsigned short*)(ws + WS_BP);

  hipMemsetAsync(Rv, 0, D_ * sizeof(float), stream);  // atomic target

  rowdot_exp_kernel<<<N_ / 4, 256, 0, stream>>>(Hf, wa, ba, tv);           // t = exp(sf+ba)
  rowdot_exp_kernel<<<M_ / 4, 256, 0, stream>>>(Hc, wa + D_, nullptr, uv); // u = exp(sc)
  hc_pack_kernel<<<256, 256, 0, stream>>>(Hc, BP, Rv);
  wt_pack_kernel<<<32, 256, 0, stream>>>(Wt, WtP);

  fused_kernel<<<N_ / 32, 512, 0, stream>>>(adj, BP, tv, uv, Rv, Hf, WtP, bt, out);
}

// Round 10
// 510.562 us; speedup vs baseline: 1.2108x; 1.0226x over previous
//
#include <hip/hip_runtime.h>
#include <hip/hip_bf16.h>
#include <stdint.h>

// Problem constants (fixed by the reference)
#define N_ 16384
#define M_ 4096
#define D_ 256
#define O_ 256

// Workspace layout (bytes), total ~10.5 MB
#define WS_T    0          // float[N]      exp(sf+ba)     64 KB
#define WS_U    65536      // float[M]      exp(sc)        16 KB
#define WS_R    81920      // float[D]      colsum(Hc)      1 KB
#define WS_LSUM 98304      // float[N]      row denoms     64 KB
#define WS_WTP  163840     // ushort        Wt packed     128 KB
#define WS_BP   294912     // ushort        Hc packed       2 MB
#define WS_ABM  2457600    // u64[N*64]     adj bit-matrix  8 MB

typedef float  f32x4  __attribute__((ext_vector_type(4)));
typedef short  short8 __attribute__((ext_vector_type(8)));

// fp32 -> bf16 (RNE). Inputs are finite so no NaN handling.
__device__ __forceinline__ unsigned short f2bf(float f) {
  uint32_t u = __float_as_uint(f);
  u += 0x7FFFu + ((u >> 16) & 1u);
  return (unsigned short)(u >> 16);
}
// packed pair fp32 -> bf16
__device__ __forceinline__ uint32_t cvtpk(float a, float b) {
  __hip_bfloat162 h = __float22bfloat162_rn(float2{a, b});
  uint32_t u;
  __builtin_memcpy(&u, &h, 4);
  return u;
}

// ---------------------------------------------------------------------------
// Prep 1: per-row dot with weight vector, then exp(dot + bias).
__global__ __launch_bounds__(256) void rowdot_exp_kernel(
    const float* __restrict__ X, const float* __restrict__ w,
    const float* __restrict__ bias, float* __restrict__ outv) {
  int wv = threadIdx.x >> 6, lane = threadIdx.x & 63;
  int row = blockIdx.x * 4 + wv;
  const float4* x4 = (const float4*)(X + (size_t)row * D_);
  const float4* w4 = (const float4*)w;
  float4 xa = x4[lane], wa4 = w4[lane];
  float s = xa.x * wa4.x + xa.y * wa4.y + xa.z * wa4.z + xa.w * wa4.w;
#pragma unroll
  for (int off = 32; off > 0; off >>= 1) s += __shfl_xor(s, off);
  if (lane == 0) outv[row] = expf(s + (bias ? bias[0] : 0.0f));
}

// ---------------------------------------------------------------------------
// Prep 2: Hc [M,D] fp32 -> BP fragment-major bf16 + colsum.
// BP[((kg*16 + cg)*64 + lane)*8 + j] = bf16(Hc[kg*32+q*8+j][cg*16+m]), lane=q*16+m.
__global__ __launch_bounds__(256) void hc_pack_kernel(
    const float* __restrict__ Hc, unsigned short* __restrict__ BP,
    float* __restrict__ R) {
  __shared__ float tile[64][65];
  __shared__ float red[4][64];
  int bk = blockIdx.x >> 2;   // 64 tiles along M (k)
  int bc = blockIdx.x & 3;    // 4 tiles along D (col)
  int k0 = bk * 64, col0 = bc * 64;
  int t = threadIdx.x;
  int lane = t & 63, wv = t >> 6;
  int m = lane & 15, q = lane >> 4;
  float colsum = 0.0f;
#pragma unroll
  for (int i = 0; i < 16; ++i) {
    int e = t + 256 * i;
    int kk = e >> 6, cc = e & 63;
    float v = Hc[(size_t)(k0 + kk) * D_ + col0 + cc];
    tile[kk][cc] = v;
    colsum += v;
  }
  red[wv][t & 63] = colsum;
  __syncthreads();
  if (t < 64)
    atomicAdd(&R[col0 + t], red[0][t] + red[1][t] + red[2][t] + red[3][t]);
#pragma unroll
  for (int t8 = 0; t8 < 2; ++t8) {
    int tile_id = t8 * 4 + wv;
    int sub = tile_id >> 2, g = tile_id & 3;
    int kgg = bk * 2 + sub;
    int cgg = bc * 4 + g;
    short8 v8;
#pragma unroll
    for (int j = 0; j < 8; ++j)
      v8[j] = (short)f2bf(tile[sub * 32 + q * 8 + j][g * 16 + m]);
    *(short8*)(BP + ((size_t)(kgg * 16 + cgg) * 64 + lane) * 8) = v8;
  }
}

// ---------------------------------------------------------------------------
// Prep 3: Wt [O,D] fp32 -> WtP fragment-major bf16 (kg 0..7, cg 0..15).
__global__ __launch_bounds__(256) void wt_pack_kernel(
    const float* __restrict__ Wt, unsigned short* __restrict__ WtP) {
  int t = blockIdx.x * 256 + threadIdx.x;    // 0..8191
  int lane = t & 63, cg = (t >> 6) & 15, kg = t >> 10;
  int m = lane & 15, q = lane >> 4;
  const float* src = Wt + (size_t)(cg * 16 + m) * D_ + kg * 32 + q * 8;
  float4 w0 = *(const float4*)src, w1 = *(const float4*)(src + 4);
  short8 v8;
  v8[0] = (short)f2bf(w0.x); v8[1] = (short)f2bf(w0.y);
  v8[2] = (short)f2bf(w0.z); v8[3] = (short)f2bf(w0.w);
  v8[4] = (short)f2bf(w1.x); v8[5] = (short)f2bf(w1.y);
  v8[6] = (short)f2bf(w1.z); v8[7] = (short)f2bf(w1.w);
  *(short8*)(WtP + (size_t)t * 8) = v8;
}

// ---------------------------------------------------------------------------
// pack_bits: ROW-CONTIGUOUS adj stream (no 16KB-strided loads -> no L1 set
// thrash). One wave processes one row at a time; lane l reads adj[r][k0+64j+l]
// (256B contiguous per instr). __ballot packs 64 k-contiguous bits -> ABM
// uint64 words (bit l of word (k0/64+j) = adj[r][k0+64j+l] != 0). Exact row
// denominators Lsum[r] = t_r * sum(adj*u) - sum(adj) in the same pass.
// Grid = 1024 x 256 thr (4 waves); wave = 4 rows. 4 blocks/CU = 16 waves/CU.
__global__ __launch_bounds__(256) void pack_bits_kernel(
    const float* __restrict__ adj, const float* __restrict__ tv,
    const float* __restrict__ uv, unsigned long long* __restrict__ ABM,
    float* __restrict__ Lsum) {
  __shared__ float u_lds[M_];   // 16 KB
  int tid = threadIdx.x;
  int w = tid >> 6, lane = tid & 63;
  for (int i = tid; i < M_; i += 256) u_lds[i] = uv[i];
  __syncthreads();
  int gw = blockIdx.x * 4 + w;

#pragma unroll 1
  for (int rr = 0; rr < 4; ++rr) {
    int r = gw * 4 + rr;
    const float* ar = adj + (size_t)r * M_;
    float su = 0.0f, sc = 0.0f;
    // depth-1 register prefetch across the 16 iters (256 k each)
    float x0 = ar[lane], x1 = ar[64 + lane], x2 = ar[128 + lane], x3 = ar[192 + lane];
#pragma unroll 1
    for (int i = 0; i < 16; ++i) {
      int k0 = i * 256;
      int k1 = (i + 1 < 16) ? k0 + 256 : 0;     // wrap: harmless reload
      float n0 = ar[k1 + lane];
      float n1 = ar[k1 + 64 + lane];
      float n2 = ar[k1 + 128 + lane];
      float n3 = ar[k1 + 192 + lane];
      unsigned long long b0 = __ballot(x0 != 0.0f);
      unsigned long long b1 = __ballot(x1 != 0.0f);
      unsigned long long b2 = __ballot(x2 != 0.0f);
      unsigned long long b3 = __ballot(x3 != 0.0f);
      su = fmaf(x0, u_lds[k0 + lane], su);
      su = fmaf(x1, u_lds[k0 + 64 + lane], su);
      su = fmaf(x2, u_lds[k0 + 128 + lane], su);
      su = fmaf(x3, u_lds[k0 + 192 + lane], su);
      sc += (x0 + x1) + (x2 + x3);
      if (lane < 4) {
        unsigned long long bb = lane == 0 ? b0 : lane == 1 ? b1 : lane == 2 ? b2 : b3;
        ABM[(size_t)r * 64 + i * 4 + lane] = bb;
      }
      x0 = n0; x1 = n1; x2 = n2; x3 = n3;
    }
#pragma unroll
    for (int off = 32; off > 0; off >>= 1) {
      su += __shfl_xor(su, off);
      sc += __shfl_xor(sc, off);
    }
    if (lane == 0) Lsum[r] = tv[r] * su - sc;
  }
}

// ---------------------------------------------------------------------------
// Build a bf16 MFMA A-fragment from 8 adj bits: slot j = bit_j ? (t*u_j - 1) : 0.
// Masking the packed bf16 pair with 0x0000 yields exact +0.0. (R7-proven.)
__device__ __forceinline__ short8 frag_bits(uint32_t bits, float t,
                                            float4 u0, float4 u1) {
  float c[8];
  c[0] = fmaf(t, u0.x, -1.0f); c[1] = fmaf(t, u0.y, -1.0f);
  c[2] = fmaf(t, u0.z, -1.0f); c[3] = fmaf(t, u0.w, -1.0f);
  c[4] = fmaf(t, u1.x, -1.0f); c[5] = fmaf(t, u1.y, -1.0f);
  c[6] = fmaf(t, u1.z, -1.0f); c[7] = fmaf(t, u1.w, -1.0f);
  union { short8 s; uint32_t u[4]; } r;
#pragma unroll
  for (int p = 0; p < 4; ++p) {
    uint32_t mlo = 0u - ((bits >> (2 * p)) & 1u);      // 0 or ~0
    uint32_t mhi = 0u - ((bits >> (2 * p + 1)) & 1u);
    r.u[p] = cvtpk(c[2 * p], c[2 * p + 1]) &
             ((mlo & 0x0000FFFFu) | (mhi & 0xFFFF0000u));
  }
  return r.s;
}

// ---------------------------------------------------------------------------
// GEMM + fused epilogue (R9 block structure, A-side from LDS bits):
//   Block = 32 rows x 256 cols x full K, 512 thr = 8 waves (4 colq x 2 khalf).
//   Bits staged once (16 KB LDS, bank-clean [kstep][row] layout) -> ZERO
//   global A traffic in the K-loop; B fragments from prepacked BP with X/Y
//   register prefetch (L1 no longer polluted by adj). Partials combined via
//   LDS fp32 atomics; attn=(C+R)/(Lsum+M)+Hf -> LDS bf16 -> O-GEMM -> relu.
// Grid = N/32 = 512, LDS ~66 KB, VGPR<=128 -> 2 blocks/CU = 16 waves/CU.
__global__ __launch_bounds__(512, 4) void gemm_kernel(
    const unsigned int* __restrict__ ABM32, const unsigned short* __restrict__ BP,
    const float* __restrict__ tv, const float* __restrict__ uv,
    const float* __restrict__ Lsum, const float* __restrict__ Rv,
    const float* __restrict__ Hf, const unsigned short* __restrict__ WtP,
    const float* __restrict__ bt, float* __restrict__ out) {
  union SM {
    struct {
      float u[M_];                   // 16 KB
      unsigned int bt[128][32];      // 16 KB  [kstep][row], bank = row
    } s;
    unsigned short attn[32][264];    // 16.9 KB (aliases u/bt after K loop)
  };
  __shared__ SM sm;
  __shared__ float part[32][260];    // 33.3 KB fp32 C accumulator

  int tid = threadIdx.x;
  int w = tid >> 6, lane = tid & 63;
  int q = lane >> 4, m = lane & 15;
  int colq = w & 3, khalf = w >> 2;
  int i0 = blockIdx.x * 32;

  for (int i = tid; i < M_; i += 512) sm.s.u[i] = uv[i];
  for (int p = tid; p < 32 * 128; p += 512) {
    int row = p >> 7, word = p & 127;          // coalesced global read
    sm.s.bt[word][row] = ABM32[(size_t)(i0 + row) * 128 + word];
  }
  {
    float* pz = &part[0][0];
    for (int i = tid; i < 32 * 260; i += 512) pz[i] = 0.0f;
  }

  float t0 = tv[i0 + m], t1 = tv[i0 + 16 + m];
  const unsigned short* bb =
      BP + ((size_t)(khalf * 64) * 16 + colq * 4) * 512 + (size_t)lane * 8;
  int kgbase = khalf * 64;

  f32x4 acc[2][4];
#pragma unroll
  for (int s = 0; s < 2; ++s)
#pragma unroll
    for (int n = 0; n < 4; ++n) acc[s][n] = (f32x4){0.f, 0.f, 0.f, 0.f};

  __syncthreads();  // u, bits, part-zero ready

  // B X/Y register prefetch: X = even local ksteps, Y = odd
  short8 BX[4], BY[4];
#pragma unroll
  for (int n = 0; n < 4; ++n) BX[n] = *(const short8*)(bb + n * 512);
#pragma unroll
  for (int n = 0; n < 4; ++n) BY[n] = *(const short8*)(bb + 8192 + n * 512);

  for (int kk = 0; kk < 64; kk += 2) {
    // ---- local kstep kk (set X); prefetch kk+2 into X
    {
      int k2 = (kk + 2) & 63;                  // wrap: harmless reload
      short8 nB[4];
#pragma unroll
      for (int n = 0; n < 4; ++n)
        nB[n] = *(const short8*)(bb + (size_t)k2 * 8192 + n * 512);
      int kg = kgbase + kk;
      uint32_t w0 = sm.s.bt[kg][m];
      uint32_t w1 = sm.s.bt[kg][16 + m];
      float4 u0 = *(const float4*)&sm.s.u[kg * 32 + q * 8];
      float4 u1 = *(const float4*)&sm.s.u[kg * 32 + q * 8 + 4];
      short8 af0 = frag_bits((w0 >> (q * 8)) & 0xffu, t0, u0, u1);
      short8 af1 = frag_bits((w1 >> (q * 8)) & 0xffu, t1, u0, u1);
#pragma unroll
      for (int n = 0; n < 4; ++n) {
        acc[0][n] = __builtin_amdgcn_mfma_f32_16x16x32_bf16(af0, BX[n], acc[0][n], 0, 0, 0);
        acc[1][n] = __builtin_amdgcn_mfma_f32_16x16x32_bf16(af1, BX[n], acc[1][n], 0, 0, 0);
      }
#pragma unroll
      for (int n = 0; n < 4; ++n) BX[n] = nB[n];
    }
    // ---- local kstep kk+1 (set Y); prefetch kk+3 into Y
    {
      int k3 = (kk + 3) & 63;
      short8 nB[4];
#pragma unroll
      for (int n = 0; n < 4; ++n)
        nB[n] = *(const short8*)(bb + (size_t)k3 * 8192 + n * 512);
      int kg = kgbase + kk + 1;
      uint32_t w0 = sm.s.bt[kg][m];
      uint32_t w1 = sm.s.bt[kg][16 + m];
      float4 u0 = *(const float4*)&sm.s.u[kg * 32 + q * 8];
      float4 u1 = *(const float4*)&sm.s.u[kg * 32 + q * 8 + 4];
      short8 af0 = frag_bits((w0 >> (q * 8)) & 0xffu, t0, u0, u1);
      short8 af1 = frag_bits((w1 >> (q * 8)) & 0xffu, t1, u0, u1);
#pragma unroll
      for (int n = 0; n < 4; ++n) {
        acc[0][n] = __builtin_amdgcn_mfma_f32_16x16x32_bf16(af0, BY[n], acc[0][n], 0, 0, 0);
        acc[1][n] = __builtin_amdgcn_mfma_f32_16x16x32_bf16(af1, BY[n], acc[1][n], 0, 0, 0);
      }
#pragma unroll
      for (int n = 0; n < 4; ++n) BY[n] = nB[n];
    }
  }

  // K-half partial C -> LDS fp32 atomic accumulate (2 adds/address)
#pragma unroll
  for (int s = 0; s < 2; ++s)
#pragma unroll
    for (int n = 0; n < 4; ++n) {
      int col = colq * 64 + n * 16 + m;
#pragma unroll
      for (int r = 0; r < 4; ++r)
        atomicAdd(&part[s * 16 + q * 4 + r][col], acc[s][n][r]);  // C/D: row=(lane>>4)*4+reg
    }
  __syncthreads();

  // attn = (C + R)/(Lsum + M) + Hf -> bf16 LDS (aliases u/bt: both dead now).
#pragma unroll
  for (int rr = 0; rr < 4; ++rr) {
    int r = w * 4 + rr;
    float invL = 1.0f / (Lsum[i0 + r] + (float)M_);
    size_t grow = (size_t)(i0 + r) * D_;
#pragma unroll
    for (int h = 0; h < 2; ++h) {
      int c = h * 128 + 2 * lane;
      float2 pv = *(const float2*)&part[r][c];
      float2 rv2 = *(const float2*)(Rv + c);
      float2 hv = *(const float2*)(Hf + grow + c);
      float v0 = fmaf(pv.x + rv2.x, invL, hv.x);
      float v1 = fmaf(pv.y + rv2.y, invL, hv.y);
      *(uint32_t*)&sm.attn[r][c] = cvtpk(v0, v1);
    }
  }
  __syncthreads();

  // O-GEMM: out = relu(attn @ Wt^T + bt). 8 waves = 2 rtiles x 4 col-64s.
  int rtile = w & 1, c64 = w >> 1;
  f32x4 facc[4];
#pragma unroll
  for (int n = 0; n < 4; ++n) facc[n] = (f32x4){0.f, 0.f, 0.f, 0.f};
#pragma unroll
  for (int kf = 0; kf < 8; ++kf) {
    short8 af = *(const short8*)&sm.attn[rtile * 16 + m][kf * 32 + q * 8];
#pragma unroll
    for (int n = 0; n < 4; ++n) {
      int cg = c64 * 4 + n;
      short8 bf = *(const short8*)(WtP + ((size_t)(kf * 16 + cg) * 64 + lane) * 8);
      facc[n] = __builtin_amdgcn_mfma_f32_16x16x32_bf16(af, bf, facc[n], 0, 0, 0);
    }
  }
#pragma unroll
  for (int n = 0; n < 4; ++n) {
    int col = c64 * 64 + n * 16 + m;
    float b = bt[col];
#pragma unroll
    for (int r = 0; r < 4; ++r) {
      size_t row = (size_t)i0 + rtile * 16 + q * 4 + r;
      out[row * O_ + col] = fmaxf(facc[n][r] + b, 0.0f);
    }
  }
}

// ---------------------------------------------------------------------------
extern "C" void kernel_launch(void* const* d_in, const int* in_sizes, int n_in,
                              void* d_out, int out_size, void* d_ws, size_t ws_size,
                              hipStream_t stream) {
  const float* Hf  = (const float*)d_in[0];  // [N,D]
  const float* Hc  = (const float*)d_in[1];  // [M,D]
  const float* adj = (const float*)d_in[2];  // [N,M]
  const float* wa  = (const float*)d_in[3];  // [2D]
  const float* ba  = (const float*)d_in[4];  // [1]
  const float* Wt  = (const float*)d_in[5];  // [O,D]
  const float* bt  = (const float*)d_in[6];  // [O]
  float* out = (float*)d_out;

  char* ws = (char*)d_ws;
  float* tv   = (float*)(ws + WS_T);
  float* uv   = (float*)(ws + WS_U);
  float* Rv   = (float*)(ws + WS_R);
  float* Lsum = (float*)(ws + WS_LSUM);
  unsigned short* WtP = (unsigned short*)(ws + WS_WTP);
  unsigned short* BP  = (unsigned short*)(ws + WS_BP);
  unsigned long long* ABM = (unsigned long long*)(ws + WS_ABM);

  hipMemsetAsync(Rv, 0, D_ * sizeof(float), stream);  // atomic target

  rowdot_exp_kernel<<<N_ / 4, 256, 0, stream>>>(Hf, wa, ba, tv);           // t = exp(sf+ba)
  rowdot_exp_kernel<<<M_ / 4, 256, 0, stream>>>(Hc, wa + D_, nullptr, uv); // u = exp(sc)
  hc_pack_kernel<<<256, 256, 0, stream>>>(Hc, BP, Rv);
  wt_pack_kernel<<<32, 256, 0, stream>>>(Wt, WtP);

  pack_bits_kernel<<<1024, 256, 0, stream>>>(adj, tv, uv, ABM, Lsum);
  gemm_kernel<<<N_ / 32, 512, 0, stream>>>((const unsigned int*)ABM, BP, tv, uv,
                                           Lsum, Rv, Hf, WtP, bt, out);
}

// Round 11
// 489.242 us; speedup vs baseline: 1.2635x; 1.0436x over previous
//
#include <hip/hip_runtime.h>
#include <hip/hip_bf16.h>
#include <stdint.h>

// Problem constants (fixed by the reference)
#define N_ 16384
#define M_ 4096
#define D_ 256
#define O_ 256

// Workspace layout (bytes), total ~44 MB
#define WS_T    0          // float[N]      exp(sf+ba)     64 KB
#define WS_U    65536      // float[M]      exp(sc)        16 KB
#define WS_R    81920      // float[D]      colsum(Hc)      1 KB
#define WS_LSUM 98304      // float[N]      row denoms     64 KB
#define WS_WTP  163840     // ushort        Wt packed     128 KB
#define WS_BP   294912     // ushort        Hc packed       2 MB
#define WS_ABM  2457600    // u64[N*64]     adj bit-matrix  8 MB
#define WS_CP   10846208   // ushort[4*N*D] split-K partials 33.5 MB

typedef float  f32x4  __attribute__((ext_vector_type(4)));
typedef short  short8 __attribute__((ext_vector_type(8)));
typedef unsigned short ushortx4 __attribute__((ext_vector_type(4)));

// fp32 -> bf16 (RNE). Inputs are finite so no NaN handling.
__device__ __forceinline__ unsigned short f2bf(float f) {
  uint32_t u = __float_as_uint(f);
  u += 0x7FFFu + ((u >> 16) & 1u);
  return (unsigned short)(u >> 16);
}
// packed pair fp32 -> bf16
__device__ __forceinline__ uint32_t cvtpk(float a, float b) {
  __hip_bfloat162 h = __float22bfloat162_rn(float2{a, b});
  uint32_t u;
  __builtin_memcpy(&u, &h, 4);
  return u;
}
__device__ __forceinline__ float bf2f(unsigned short v) {
  return __uint_as_float((uint32_t)v << 16);
}

// ---------------------------------------------------------------------------
// Prep 1: per-row dot with weight vector, then exp(dot + bias).
__global__ __launch_bounds__(256) void rowdot_exp_kernel(
    const float* __restrict__ X, const float* __restrict__ w,
    const float* __restrict__ bias, float* __restrict__ outv) {
  int wv = threadIdx.x >> 6, lane = threadIdx.x & 63;
  int row = blockIdx.x * 4 + wv;
  const float4* x4 = (const float4*)(X + (size_t)row * D_);
  const float4* w4 = (const float4*)w;
  float4 xa = x4[lane], wa4 = w4[lane];
  float s = xa.x * wa4.x + xa.y * wa4.y + xa.z * wa4.z + xa.w * wa4.w;
#pragma unroll
  for (int off = 32; off > 0; off >>= 1) s += __shfl_xor(s, off);
  if (lane == 0) outv[row] = expf(s + (bias ? bias[0] : 0.0f));
}

// ---------------------------------------------------------------------------
// Prep 2: Hc [M,D] fp32 -> BP fragment-major bf16 + colsum.
// BP[((kg*16 + cg)*64 + lane)*8 + j] = bf16(Hc[kg*32+q*8+j][cg*16+m]), lane=q*16+m.
__global__ __launch_bounds__(256) void hc_pack_kernel(
    const float* __restrict__ Hc, unsigned short* __restrict__ BP,
    float* __restrict__ R) {
  __shared__ float tile[64][65];
  __shared__ float red[4][64];
  int bk = blockIdx.x >> 2;   // 64 tiles along M (k)
  int bc = blockIdx.x & 3;    // 4 tiles along D (col)
  int k0 = bk * 64, col0 = bc * 64;
  int t = threadIdx.x;
  int lane = t & 63, wv = t >> 6;
  int m = lane & 15, q = lane >> 4;
  float colsum = 0.0f;
#pragma unroll
  for (int i = 0; i < 16; ++i) {
    int e = t + 256 * i;
    int kk = e >> 6, cc = e & 63;
    float v = Hc[(size_t)(k0 + kk) * D_ + col0 + cc];
    tile[kk][cc] = v;
    colsum += v;
  }
  red[wv][t & 63] = colsum;
  __syncthreads();
  if (t < 64)
    atomicAdd(&R[col0 + t], red[0][t] + red[1][t] + red[2][t] + red[3][t]);
#pragma unroll
  for (int t8 = 0; t8 < 2; ++t8) {
    int tile_id = t8 * 4 + wv;
    int sub = tile_id >> 2, g = tile_id & 3;
    int kgg = bk * 2 + sub;
    int cgg = bc * 4 + g;
    short8 v8;
#pragma unroll
    for (int j = 0; j < 8; ++j)
      v8[j] = (short)f2bf(tile[sub * 32 + q * 8 + j][g * 16 + m]);
    *(short8*)(BP + ((size_t)(kgg * 16 + cgg) * 64 + lane) * 8) = v8;
  }
}

// ---------------------------------------------------------------------------
// Prep 3: Wt [O,D] fp32 -> WtP fragment-major bf16 (kg 0..7, cg 0..15).
__global__ __launch_bounds__(256) void wt_pack_kernel(
    const float* __restrict__ Wt, unsigned short* __restrict__ WtP) {
  int t = blockIdx.x * 256 + threadIdx.x;    // 0..8191
  int lane = t & 63, cg = (t >> 6) & 15, kg = t >> 10;
  int m = lane & 15, q = lane >> 4;
  const float* src = Wt + (size_t)(cg * 16 + m) * D_ + kg * 32 + q * 8;
  float4 w0 = *(const float4*)src, w1 = *(const float4*)(src + 4);
  short8 v8;
  v8[0] = (short)f2bf(w0.x); v8[1] = (short)f2bf(w0.y);
  v8[2] = (short)f2bf(w0.z); v8[3] = (short)f2bf(w0.w);
  v8[4] = (short)f2bf(w1.x); v8[5] = (short)f2bf(w1.y);
  v8[6] = (short)f2bf(w1.z); v8[7] = (short)f2bf(w1.w);
  *(short8*)(WtP + (size_t)t * 8) = v8;
}

// ---------------------------------------------------------------------------
// pack_bits v2: row-contiguous adj stream with 2 KB/wave in flight.
// Wave = 2 rows interleaved; 8 blocks/CU -> 32 waves/CU -> 64 KB in flight/CU
// (covers 900cy x 24.6B/cy = 22 KB) -> true HBM-bound. __ballot packs 64
// k-contiguous bits; exact row denoms Lsum[r] = t_r*sum(adj*u) - sum(adj).
// Grid = 2048 x 256 thr (4 waves x 2 rows = 8 rows/block).
__global__ __launch_bounds__(256) void pack_bits_kernel(
    const float* __restrict__ adj, const float* __restrict__ tv,
    const float* __restrict__ uv, unsigned long long* __restrict__ ABM,
    float* __restrict__ Lsum) {
  __shared__ float u_lds[M_];   // 16 KB
  int tid = threadIdx.x;
  int w = tid >> 6, lane = tid & 63;
  for (int i = tid; i < M_; i += 256) u_lds[i] = uv[i];
  __syncthreads();
  int r0 = (blockIdx.x * 4 + w) * 2;
  const float* arA = adj + (size_t)r0 * M_;
  const float* arB = arA + M_;
  float suA = 0.f, scA = 0.f, suB = 0.f, scB = 0.f;

  // depth-1 prefetch across iters, 2 rows x 4 loads = 2 KB/wave in flight
  float a0 = arA[lane], a1 = arA[64 + lane], a2 = arA[128 + lane], a3 = arA[192 + lane];
  float b0 = arB[lane], b1 = arB[64 + lane], b2 = arB[128 + lane], b3 = arB[192 + lane];
#pragma unroll 1
  for (int i = 0; i < 16; ++i) {
    int k0 = i * 256;
    int k1 = (i + 1 < 16) ? k0 + 256 : 0;     // wrap: harmless reload
    float na0 = arA[k1 + lane],       na1 = arA[k1 + 64 + lane];
    float na2 = arA[k1 + 128 + lane], na3 = arA[k1 + 192 + lane];
    float nb0 = arB[k1 + lane],       nb1 = arB[k1 + 64 + lane];
    float nb2 = arB[k1 + 128 + lane], nb3 = arB[k1 + 192 + lane];

    unsigned long long wA0 = __ballot(a0 != 0.0f), wA1 = __ballot(a1 != 0.0f);
    unsigned long long wA2 = __ballot(a2 != 0.0f), wA3 = __ballot(a3 != 0.0f);
    unsigned long long wB0 = __ballot(b0 != 0.0f), wB1 = __ballot(b1 != 0.0f);
    unsigned long long wB2 = __ballot(b2 != 0.0f), wB3 = __ballot(b3 != 0.0f);
    suA = fmaf(a0, u_lds[k0 + lane], suA);
    suA = fmaf(a1, u_lds[k0 + 64 + lane], suA);
    suA = fmaf(a2, u_lds[k0 + 128 + lane], suA);
    suA = fmaf(a3, u_lds[k0 + 192 + lane], suA);
    scA += (a0 + a1) + (a2 + a3);
    suB = fmaf(b0, u_lds[k0 + lane], suB);
    suB = fmaf(b1, u_lds[k0 + 64 + lane], suB);
    suB = fmaf(b2, u_lds[k0 + 128 + lane], suB);
    suB = fmaf(b3, u_lds[k0 + 192 + lane], suB);
    scB += (b0 + b1) + (b2 + b3);
    if (lane < 8) {
      int sel = lane & 3;
      unsigned long long vA = sel == 0 ? wA0 : sel == 1 ? wA1 : sel == 2 ? wA2 : wA3;
      unsigned long long vB = sel == 0 ? wB0 : sel == 1 ? wB1 : sel == 2 ? wB2 : wB3;
      int r = (lane < 4) ? r0 : r0 + 1;
      ABM[(size_t)r * 64 + i * 4 + sel] = (lane < 4) ? vA : vB;
    }
    a0 = na0; a1 = na1; a2 = na2; a3 = na3;
    b0 = nb0; b1 = nb1; b2 = nb2; b3 = nb3;
  }
#pragma unroll
  for (int off = 32; off > 0; off >>= 1) {
    suA += __shfl_xor(suA, off); scA += __shfl_xor(scA, off);
    suB += __shfl_xor(suB, off); scB += __shfl_xor(scB, off);
  }
  if (lane == 0) {
    Lsum[r0] = tv[r0] * suA - scA;
    Lsum[r0 + 1] = tv[r0 + 1] * suB - scB;
  }
}

// ---------------------------------------------------------------------------
// Build a bf16 MFMA A-fragment from 8 adj bits: slot j = bit_j ? (t*u_j - 1) : 0.
// Masking the packed bf16 pair with 0x0000 yields exact +0.0. (R7-proven.)
__device__ __forceinline__ short8 frag_bits(uint32_t bits, float t,
                                            float4 u0, float4 u1) {
  float c[8];
  c[0] = fmaf(t, u0.x, -1.0f); c[1] = fmaf(t, u0.y, -1.0f);
  c[2] = fmaf(t, u0.z, -1.0f); c[3] = fmaf(t, u0.w, -1.0f);
  c[4] = fmaf(t, u1.x, -1.0f); c[5] = fmaf(t, u1.y, -1.0f);
  c[6] = fmaf(t, u1.z, -1.0f); c[7] = fmaf(t, u1.w, -1.0f);
  union { short8 s; uint32_t u[4]; } r;
#pragma unroll
  for (int p = 0; p < 4; ++p) {
    uint32_t mlo = 0u - ((bits >> (2 * p)) & 1u);      // 0 or ~0
    uint32_t mhi = 0u - ((bits >> (2 * p + 1)) & 1u);
    r.u[p] = cvtpk(c[2 * p], c[2 * p + 1]) &
             ((mlo & 0x0000FFFFu) | (mhi & 0xFFFF0000u));
  }
  return r.s;
}

// ---------------------------------------------------------------------------
// GEMM v2: 64-row x 256-col blocks, 1024 thr = 16 waves (4 colq x 4 ksub).
// Each wave: 4 row-tiles x 4 col-groups x 1024-K quarter (32 ksteps) ->
// every B fragment feeds 4 MFMAs (2x better B economy than R10). Bits in
// LDS (padded bank-clean [row][word]); u table in LDS; B from prepacked BP
// with depth-1 register prefetch; barrier-free K loop. Split-K=4 partials
// stored bf16 to Cp. Grid = N/64 = 256 -> 1 block/CU = 16 waves/CU.
__global__ __launch_bounds__(1024, 4) void gemm_kernel(
    const unsigned int* __restrict__ ABM32, const unsigned short* __restrict__ BP,
    const float* __restrict__ tv, const float* __restrict__ uv,
    unsigned short* __restrict__ Cp) {
  __shared__ unsigned int bt2[64][129];   // 33 KB, pad -> bank=(row+word)%32
  __shared__ float u_lds[M_];             // 16 KB
  int tid = threadIdx.x;
  int w = tid >> 6, lane = tid & 63;
  int q = lane >> 4, m = lane & 15;
  int colq = w >> 2, ksub = w & 3;
  int i0 = blockIdx.x * 64;

  // B base + first-kstep prefetch issued BEFORE the barrier (no LDS dep)
  const unsigned short* bbase = BP + (size_t)(colq * 4) * 512 + (size_t)lane * 8;
  int kg0 = ksub * 32;
  short8 curB[4];
#pragma unroll
  for (int n = 0; n < 4; ++n)
    curB[n] = *(const short8*)(bbase + ((size_t)kg0 * 16 + n) * 512);
  float t0 = tv[i0 + m], t1 = tv[i0 + 16 + m];
  float t2 = tv[i0 + 32 + m], t3 = tv[i0 + 48 + m];

  for (int i = tid; i < M_; i += 1024) u_lds[i] = uv[i];
  for (int p = tid; p < 8192; p += 1024) {
    int row = p >> 7, word = p & 127;     // coalesced global; conflict-free LDS
    bt2[row][word] = ABM32[(size_t)(i0 + row) * 128 + word];
  }

  f32x4 acc[4][4];
#pragma unroll
  for (int s = 0; s < 4; ++s)
#pragma unroll
    for (int n = 0; n < 4; ++n) acc[s][n] = (f32x4){0.f, 0.f, 0.f, 0.f};

  __syncthreads();  // bits + u ready (only barrier)

  for (int it = 0; it < 32; ++it) {
    int kg = kg0 + it;
    int kn = (it + 1 < 32) ? kg + 1 : kg0;   // wrap: harmless reload
    short8 nB[4];
#pragma unroll
    for (int n = 0; n < 4; ++n)
      nB[n] = *(const short8*)(bbase + ((size_t)kn * 16 + n) * 512);

    float4 u0 = *(const float4*)&u_lds[kg * 32 + q * 8];
    float4 u1 = *(const float4*)&u_lds[kg * 32 + q * 8 + 4];
    uint32_t b0 = bt2[m][kg],      b1 = bt2[16 + m][kg];
    uint32_t b2 = bt2[32 + m][kg], b3 = bt2[48 + m][kg];
    int sh = q * 8;
    short8 af0 = frag_bits((b0 >> sh) & 0xffu, t0, u0, u1);
    short8 af1 = frag_bits((b1 >> sh) & 0xffu, t1, u0, u1);
    short8 af2 = frag_bits((b2 >> sh) & 0xffu, t2, u0, u1);
    short8 af3 = frag_bits((b3 >> sh) & 0xffu, t3, u0, u1);
#pragma unroll
    for (int n = 0; n < 4; ++n) {
      acc[0][n] = __builtin_amdgcn_mfma_f32_16x16x32_bf16(af0, curB[n], acc[0][n], 0, 0, 0);
      acc[1][n] = __builtin_amdgcn_mfma_f32_16x16x32_bf16(af1, curB[n], acc[1][n], 0, 0, 0);
      acc[2][n] = __builtin_amdgcn_mfma_f32_16x16x32_bf16(af2, curB[n], acc[2][n], 0, 0, 0);
      acc[3][n] = __builtin_amdgcn_mfma_f32_16x16x32_bf16(af3, curB[n], acc[3][n], 0, 0, 0);
    }
#pragma unroll
    for (int n = 0; n < 4; ++n) curB[n] = nB[n];
  }

  // split-K partial -> bf16 plain stores, plane ksub
  unsigned short* cpb = Cp + (size_t)ksub * N_ * D_;
#pragma unroll
  for (int s = 0; s < 4; ++s)
#pragma unroll
    for (int n = 0; n < 4; ++n) {
      int col = colq * 64 + n * 16 + m;
#pragma unroll
      for (int r = 0; r < 4; ++r) {
        size_t row = (size_t)i0 + s * 16 + q * 4 + r;  // C/D: row=(lane>>4)*4+reg
        cpb[row * D_ + col] = f2bf(acc[s][n][r]);
      }
    }
}

// ---------------------------------------------------------------------------
// Epilogue: attn = (sum of 4 Cp + R)/(Lsum + M) + Hf -> LDS bf16 -> relu(attn@Wt^T+bt)
__global__ __launch_bounds__(256, 4) void epilogue_kernel(
    const unsigned short* __restrict__ Cp, const float* __restrict__ Lsum,
    const float* __restrict__ Rv, const float* __restrict__ Hf,
    const unsigned short* __restrict__ WtP, const float* __restrict__ bt,
    float* __restrict__ out) {
  __shared__ alignas(16) unsigned short attn[32][264];  // +8 pad
  int tid = threadIdx.x;
  int w = tid >> 6, lane = tid & 63;
  int rtile = w & 1, chalf = w >> 1;
  int q = lane >> 4, m = lane & 15;
  int i0 = blockIdx.x * 32;

  float4 rv = *(const float4*)(Rv + lane * 4);
#pragma unroll
  for (int rr = 0; rr < 8; ++rr) {
    int r = w * 8 + rr;                       // wave w owns rows w*8..w*8+7
    size_t row = (size_t)i0 + r;
    float invL = 1.0f / (Lsum[row] + (float)M_);
    ushortx4 c0 = *(const ushortx4*)(Cp + row * D_ + lane * 4);
    ushortx4 c1 = *(const ushortx4*)(Cp + ((size_t)N_ + row) * D_ + lane * 4);
    ushortx4 c2 = *(const ushortx4*)(Cp + ((size_t)2 * N_ + row) * D_ + lane * 4);
    ushortx4 c3 = *(const ushortx4*)(Cp + ((size_t)3 * N_ + row) * D_ + lane * 4);
    float4 hv = *(const float4*)(Hf + row * D_ + lane * 4);
    float s0 = (bf2f(c0[0]) + bf2f(c1[0])) + (bf2f(c2[0]) + bf2f(c3[0]));
    float s1 = (bf2f(c0[1]) + bf2f(c1[1])) + (bf2f(c2[1]) + bf2f(c3[1]));
    float s2 = (bf2f(c0[2]) + bf2f(c1[2])) + (bf2f(c2[2]) + bf2f(c3[2]));
    float s3 = (bf2f(c0[3]) + bf2f(c1[3])) + (bf2f(c2[3]) + bf2f(c3[3]));
    attn[r][lane * 4 + 0] = f2bf(fmaf(s0 + rv.x, invL, hv.x));
    attn[r][lane * 4 + 1] = f2bf(fmaf(s1 + rv.y, invL, hv.y));
    attn[r][lane * 4 + 2] = f2bf(fmaf(s2 + rv.z, invL, hv.z));
    attn[r][lane * 4 + 3] = f2bf(fmaf(s3 + rv.w, invL, hv.w));
  }
  __syncthreads();

  f32x4 facc[8];
#pragma unroll
  for (int n = 0; n < 8; ++n) facc[n] = (f32x4){0.f, 0.f, 0.f, 0.f};
  const unsigned short* wwave = WtP + (size_t)chalf * 4096 + (size_t)lane * 8;
#pragma unroll
  for (int kf = 0; kf < 8; ++kf) {
    short8 af = *(const short8*)&attn[rtile * 16 + m][kf * 32 + q * 8];
#pragma unroll
    for (int n = 0; n < 8; ++n) {
      short8 bf = *(const short8*)(wwave + ((size_t)kf * 16 + n) * 512);
      facc[n] = __builtin_amdgcn_mfma_f32_16x16x32_bf16(af, bf, facc[n], 0, 0, 0);
    }
  }
#pragma unroll
  for (int n = 0; n < 8; ++n) {
    int col = chalf * 128 + n * 16 + m;
    float b = bt[col];
#pragma unroll
    for (int r = 0; r < 4; ++r) {
      size_t row = (size_t)i0 + rtile * 16 + q * 4 + r;
      out[row * O_ + col] = fmaxf(facc[n][r] + b, 0.0f);
    }
  }
}

// ---------------------------------------------------------------------------
extern "C" void kernel_launch(void* const* d_in, const int* in_sizes, int n_in,
                              void* d_out, int out_size, void* d_ws, size_t ws_size,
                              hipStream_t stream) {
  const float* Hf  = (const float*)d_in[0];  // [N,D]
  const float* Hc  = (const float*)d_in[1];  // [M,D]
  const float* adj = (const float*)d_in[2];  // [N,M]
  const float* wa  = (const float*)d_in[3];  // [2D]
  const float* ba  = (const float*)d_in[4];  // [1]
  const float* Wt  = (const float*)d_in[5];  // [O,D]
  const float* bt  = (const float*)d_in[6];  // [O]
  float* out = (float*)d_out;

  char* ws = (char*)d_ws;
  float* tv   = (float*)(ws + WS_T);
  float* uv   = (float*)(ws + WS_U);
  float* Rv   = (float*)(ws + WS_R);
  float* Lsum = (float*)(ws + WS_LSUM);
  unsigned short* WtP = (unsigned short*)(ws + WS_WTP);
  unsigned short* BP  = (unsigned short*)(ws + WS_BP);
  unsigned long long* ABM = (unsigned long long*)(ws + WS_ABM);
  unsigned short* Cp  = (unsigned short*)(ws + WS_CP);

  hipMemsetAsync(Rv, 0, D_ * sizeof(float), stream);  // atomic target

  rowdot_exp_kernel<<<N_ / 4, 256, 0, stream>>>(Hf, wa, ba, tv);           // t = exp(sf+ba)
  rowdot_exp_kernel<<<M_ / 4, 256, 0, stream>>>(Hc, wa + D_, nullptr, uv); // u = exp(sc)
  hc_pack_kernel<<<256, 256, 0, stream>>>(Hc, BP, Rv);
  wt_pack_kernel<<<32, 256, 0, stream>>>(Wt, WtP);

  pack_bits_kernel<<<2048, 256, 0, stream>>>(adj, tv, uv, ABM, Lsum);
  gemm_kernel<<<N_ / 64, 1024, 0, stream>>>((const unsigned int*)ABM, BP, tv, uv, Cp);
  epilogue_kernel<<<N_ / 32, 256, 0, stream>>>(Cp, Lsum, Rv, Hf, WtP, bt, out);
}